// Round 11
// baseline (267.537 us; speedup 1.0000x reference)
//
#include <hip/hip_runtime.h>

#define NN 1024
#define NW 32            // u32 words per full 1024-bit row
#define KMAX 640         // max #non-roots (P(K>640) < 1e-14)
#define KW 10            // u64 words per compact row
#define KWP 11           // padded LDS row stride (u64)
#define INF_KEY 0x7FFFFFFFu
#define NOTFOUND_BASE (1u << 21)

typedef unsigned int u32;
typedef unsigned long long u64;
typedef unsigned short u16;

__device__ __forceinline__ u64 shflxor64(u64 v, int m) {
    return (u64)__shfl_xor((long long)v, m);
}
__device__ __forceinline__ u64 rdl64(u64 v, int s) {   // broadcast lane s (uniform s)
    u32 lo = (u32)__builtin_amdgcn_readlane((int)(u32)v, s);
    u32 hi = (u32)__builtin_amdgcn_readlane((int)(u32)(v >> 32), s);
    return ((u64)hi << 32) | (u64)lo;
}
__device__ __forceinline__ u64 transpose64(u64 x, int lane) {
    #pragma unroll
    for (int st = 32; st >= 1; st >>= 1) {
        u64 mlo = (st == 32) ? 0x00000000FFFFFFFFull :
                  (st == 16) ? 0x0000FFFF0000FFFFull :
                  (st == 8)  ? 0x00FF00FF00FF00FFull :
                  (st == 4)  ? 0x0F0F0F0F0F0F0F0Full :
                  (st == 2)  ? 0x3333333333333333ull : 0x5555555555555555ull;
        u64 y = shflxor64(x, st);
        x = ((lane & st) == 0) ? ((x & mlo) | ((y & mlo) << st))
                               : ((x & ~mlo) | ((y & ~mlo) >> st));
    }
    return x;
}

// ---- K1: edge hard bits -> E ----
__global__ void edge_bits_kernel(const float* __restrict__ ep, const float* __restrict__ ge,
                                 u32* __restrict__ E)
{
    int idx = blockIdx.x * blockDim.x + threadIdx.x;
    float p = ep[idx];
    float2 g = reinterpret_cast<const float2*>(ge)[idx];
    bool hard = (p + g.x) > ((1.0f - p) + g.y);
    u64 m = __ballot(hard);
    int lane = threadIdx.x & 63;
    if ((lane & 31) == 0) E[idx >> 5] = (u32)(m >> (lane & 32));
}

// ---- K2: fused roots + seed + compact + blocked closure ----
// LDS layout (bytes): Elds 0..81920 | BqL 81920..138240 | key 138240..142336 |
// npl_node 142336..143616 | npl_rank 143616..144896 | rootm 144896..145024 |
// rootpre 145024..145152 | misc 145152..145216.  Phase B: A = 0..56320 (dead Elds).
__global__ __launch_bounds__(1024) void bfs_fused(
    const float* __restrict__ rp, const float* __restrict__ gr,
    const u32* __restrict__ Eg, u64* __restrict__ Bq_g,
    u16* __restrict__ posof_g, u32* __restrict__ meta_g)
{
    extern __shared__ char smc[];
    u32* Elds     = (u32*)smc;
    u64* BqL      = (u64*)(smc + 81920);
    u32* key      = (u32*)(smc + 138240);
    u16* npl_node = (u16*)(smc + 142336);
    u16* npl_rank = (u16*)(smc + 143616);
    u32* rootm    = (u32*)(smc + 144896);
    u32* rootpre  = (u32*)(smc + 145024);
    u32* misc     = (u32*)(smc + 145152);
    u64* A        = (u64*)smc;                    // phase B only

    const int tid  = threadIdx.x;
    const int lane = tid & 63;
    const int wid  = tid >> 6;

    // roots
    float p0 = rp[tid];
    float2 g0 = reinterpret_cast<const float2*>(gr)[tid];
    bool isroot = (p0 + g0.x) > ((1.0f - p0) + g0.y);
    u64 rm = __ballot(isroot);
    if (lane == 0) { rootm[wid * 2] = (u32)rm; rootm[wid * 2 + 1] = (u32)(rm >> 32); }
    __syncthreads();
    if (tid == 0) {
        u32 s = 0;
        #pragma unroll
        for (int w = 0; w < 32; ++w) { rootpre[w] = s; s += __popc(rootm[w]); }
    }
    __syncthreads();

    int rootsbelow = (int)rootpre[tid >> 5] + __popc(rootm[tid >> 5] & ((1u << (tid & 31)) - 1u));
    int nrank = tid - rootsbelow;

    // copy nonroot rows of E into Elds (by nonroot rank)
    if (!isroot) {
        const uint4* src = (const uint4*)(Eg + (size_t)tid * NW);
        uint4* dst = (uint4*)(Elds + nrank * NW);
        #pragma unroll
        for (int k = 0; k < 8; ++k) dst[k] = src[k];
    }

    // seed scan: rank of first root hitting node tid (global root rows, L2-hot)
    int fr = -1;
    if (!isroot) {
        int rrank = 0;
        for (int i2 = 0; i2 < NN; ++i2) {
            if ((rootm[i2 >> 5] >> (i2 & 31)) & 1u) {
                u32 wv = Eg[(size_t)i2 * NW + (tid >> 5)];
                if (fr < 0 && ((wv >> (tid & 31)) & 1u)) fr = rrank;
                ++rrank;
                if (__all(fr >= 0)) break;
            }
        }
    }
    u32 mykey = isroot ? INF_KEY
                       : (fr >= 0 ? (((u32)fr << 10) | (u32)tid) : (NOTFOUND_BASE | (u32)tid));
    key[tid] = mykey;
    __syncthreads();

    // rank-sort by counting
    int pos = 0, tl = 0, Kc = 0;
    {
        const uint4* k4 = (const uint4*)key;
        for (int q = 0; q < 256; ++q) {
            uint4 kk = k4[q];
            pos += (kk.x < mykey) + (kk.y < mykey) + (kk.z < mykey) + (kk.w < mykey);
            tl  += (kk.x < NOTFOUND_BASE) + (kk.y < NOTFOUND_BASE) + (kk.z < NOTFOUND_BASE) + (kk.w < NOTFOUND_BASE);
            Kc  += (kk.x != INF_KEY) + (kk.y != INF_KEY) + (kk.z != INF_KEY) + (kk.w != INF_KEY);
        }
    }
    if (!isroot && pos < KMAX) { npl_node[pos] = (u16)tid; npl_rank[pos] = (u16)nrank; }
    posof_g[tid] = isroot ? (u16)0xFFFF : (u16)pos;
    if (tid == 0) {
        u32 t2 = (u32)min(tl, KMAX), k2 = (u32)min(Kc, KMAX);
        misc[0] = t2; misc[1] = k2; meta_g[0] = t2;
    }
    __syncthreads();

    const int tail = (int)misc[0];
    const int K    = (int)misc[1];

    // compactB: Bq[s][t] = E[node(s)][node(t)]  (straight into phase-B LDS region)
    for (int it2 = tid; it2 < K * KW; it2 += 1024) {
        int s = it2 / KW, w = it2 - s * KW;
        const u32* row = Elds + (int)npl_rank[s] * NW;
        u64 acc = 0; int cb = w * 64;
        for (int b = 0; b < 64; ++b) {
            int t = cb + b;
            if (t < K) {
                int j = npl_node[t];
                acc |= ((u64)((row[j >> 5] >> (j & 31)) & 1u)) << b;
            }
        }
        BqL[s * KWP + w] = acc;
    }
    __syncthreads();
    // init A over dead Elds region
    for (int it2 = tid; it2 < tail * KWP; it2 += 1024) {
        int r = it2 / KWP, w = it2 - r * KWP;
        A[it2] = (w == (r >> 6)) ? (1ull << (r & 63)) : 0ull;
    }
    __syncthreads();

    const int nb = (tail + 63) >> 6;

    auto serial_block = [&](int p) {
        const int b0 = p << 6;
        const int rem = min(64, tail - b0);
        const int sp = b0 + lane;
        const bool valid = lane < rem;
        int wph[KW];
        #pragma unroll
        for (int w = 0; w < KW; ++w) { int ww = w + p; wph[w] = (ww >= KW) ? ww - KW : ww; }
        u64 a[KW], b[KW];
        #pragma unroll
        for (int w = 0; w < KW; ++w) {
            a[w] = valid ? A[sp * KWP + wph[w]]   : 0ull;
            b[w] = valid ? BqL[sp * KWP + wph[w]] : 0ull;
        }
        const u64 Dg = b[0];
        #pragma unroll 64
        for (int s = 0; s < 64; ++s) {
            u64 hrow = rdl64(Dg & ~a[0], s);
            if (hrow) {
                bool h = (((hrow >> lane) & 1ull) != 0ull) && (lane > s);
                u64 hm = h ? ~0ull : 0ull;
                #pragma unroll
                for (int w = 0; w < KW; ++w) {
                    u64 sw = rdl64(a[w], s);
                    a[w] |= sw & hm;
                }
            }
        }
        if (valid) {
            #pragma unroll
            for (int w = 0; w < KW; ++w) {
                A[sp * KWP + wph[w]]   = a[w];
                BqL[sp * KWP + wph[w]] = b[w] & ~a[w];
            }
        }
    };

    auto near_cross = [&](int ps) {
        if ((wid & 3) == 0) return;                  // keep SIMD0 clear
        int widx = wid - 1 - (wid >> 2);
        if (widx >= KW) return;
        const int sb0 = ps << 6;
        const int b0t = sb0 + 64;
        if (b0t >= tail) return;
        const int wt = b0t >> 6;
        u64 x = transpose64(BqL[(sb0 + lane) * KWP + wt], lane);
        int t = b0t + lane;
        if (t < tail && x) {
            u64 acc = 0, m = x;
            while (m) {
                int s = __ffsll((long long)m) - 1; m &= m - 1;
                acc |= A[(sb0 + s) * KWP + widx];
            }
            A[t * KWP + widx] |= acc;
        }
    };

    auto far_cross = [&](int ps) {
        if ((wid & 3) == 0) return;                  // SIMDs 1-3 only (12 workers)
        int widx = wid - 1 - (wid >> 2);
        const int sb0 = ps << 6;
        const int t0 = sb0 + 128 + (widx << 6);
        if (t0 >= tail) return;
        const int wt = t0 >> 6;
        u64 x = transpose64(BqL[(sb0 + lane) * KWP + wt], lane);
        int t = t0 + lane;
        if (t < tail && x) {
            u64 acc[KW];
            #pragma unroll
            for (int w = 0; w < KW; ++w) acc[w] = 0ull;
            u64 m = x;
            while (m) {
                int s = __ffsll((long long)m) - 1; m &= m - 1;
                const u64* Ar = A + (size_t)(sb0 + s) * KWP;
                #pragma unroll
                for (int w = 0; w < KW; ++w) acc[w] |= Ar[w];
            }
            u64* At = A + (size_t)t * KWP;
            #pragma unroll
            for (int w = 0; w < KW; ++w) At[w] |= acc[w];
        }
    };

    if (nb > 0) {
        if (wid == 0) {
            __builtin_amdgcn_s_setprio(1); serial_block(0); __builtin_amdgcn_s_setprio(0);
        }
        __syncthreads();
        for (int p = 1; p < nb; ++p) {
            near_cross(p - 1);
            __syncthreads();
            if (wid == 0) {
                __builtin_amdgcn_s_setprio(1); serial_block(p); __builtin_amdgcn_s_setprio(0);
            } else {
                far_cross(p - 1);
            }
            __syncthreads();
        }
    }
    __syncthreads();
    for (int it2 = tid; it2 < tail * KW; it2 += 1024) {
        int r = it2 / KW, w = it2 - r * KW;
        Bq_g[it2] = BqL[r * KWP + w];
    }
}

// ---- K3: expand to f32 output ----
__global__ __launch_bounds__(256) void final_expand(
    const u32* __restrict__ E, const u64* __restrict__ Bq_g,
    const u16* __restrict__ posof_g, const u32* __restrict__ meta_g,
    float4* __restrict__ out)
{
    int gid = blockIdx.x * 256 + threadIdx.x;
    int i = gid >> 8;
    int j0 = (gid & 255) << 2;
    u32 tail = meta_g[0];
    u32 pi = posof_g[i];
    float r[4] = {0.f, 0.f, 0.f, 0.f};
    if (pi == 0xFFFFu) {                             // root row: E & ~root (self is root-excluded via posof)
        u32 wv = E[(size_t)i * NW + (j0 >> 5)];
        #pragma unroll
        for (int t = 0; t < 4; ++t) {
            u32 pj = posof_g[j0 + t];
            bool nz = ((wv >> ((j0 & 31) + t)) & 1u) && (pj != 0xFFFFu);
            r[t] = nz ? 1.0f : 0.0f;
        }
    } else if (pi < tail) {                          // processed nonroot row
        const u64* row = Bq_g + (size_t)pi * KW;
        #pragma unroll
        for (int t = 0; t < 4; ++t) {
            u32 pj = posof_g[j0 + t];
            if (pj != 0xFFFFu && pj < (u32)KMAX) {
                u64 wv = row[pj >> 6];
                r[t] = ((wv >> (pj & 63)) & 1ull) ? 1.0f : 0.0f;
            }
        }
    }
    out[gid] = make_float4(r[0], r[1], r[2], r[3]);
}

extern "C" void kernel_launch(void* const* d_in, const int* in_sizes, int n_in,
                              void* d_out, int out_size, void* d_ws, size_t ws_size,
                              hipStream_t stream) {
    const float* root_probs = (const float*)d_in[0];
    const float* edge_probs = (const float*)d_in[1];
    const float* g_roots    = (const float*)d_in[2];
    const float* g_edges    = (const float*)d_in[3];

    char* ws = (char*)d_ws;
    u32* E       = (u32*)(ws);                 // 131072 B
    u64* Bq_g    = (u64*)(ws + 131072);        // 51200 B
    u16* posof_g = (u16*)(ws + 182272);        // 2048 B
    u32* meta_g  = (u32*)(ws + 184320);        // 64 B

    edge_bits_kernel<<<NN * NN / 256, 256, 0, stream>>>(edge_probs, g_edges, E);

    size_t lds = 145216;
    hipFuncSetAttribute((const void*)bfs_fused,
                        hipFuncAttributeMaxDynamicSharedMemorySize, (int)lds);
    bfs_fused<<<1, NN, lds, stream>>>(root_probs, g_roots, E, Bq_g, posof_g, meta_g);

    final_expand<<<NN * NN / 4 / 256, 256, 0, stream>>>(E, Bq_g, posof_g, meta_g,
                                                        (float4*)d_out);
}